// Round 4
// baseline (892.443 us; speedup 1.0000x reference)
//
#include <hip/hip_runtime.h>
#include <math.h>

// Problem shapes (fixed by setup_inputs)
#define BB 16
#define NN 16384
#define DD 256      // == O
#define TPB 128     // tiles per batch
#define TROWS 128   // rows per tile (TPB*TROWS == NN)
#define NBLK 1024   // persistent grid: each block does 2 tiles per phase

// Single persistent kernel. Sync via device-scope atomics + threadfence.
// Deadlock-free: a block's phase-2 tiles == its phase-1 tiles, so any set of
// blocks reaching a phase-2 wait has itself completed the producing phase-1
// work; avgw spinners (64) can never hold all CU slots (grid=1024, 256 CUs).
__global__ __launch_bounds__(256, 4) void fused_all(
    const float* __restrict__ x, const float* __restrict__ Wq,
    const float* __restrict__ bq, const float* __restrict__ Wk,
    const float* __restrict__ bk,
    float* __restrict__ part, float* __restrict__ v, float* __restrict__ c,
    float* __restrict__ scores, float* __restrict__ pm, float* __restrict__ pz,
    float* __restrict__ pP, float* __restrict__ Mb, float* __restrict__ rZb,
    int* __restrict__ ctrl, float* __restrict__ out_agg, float* __restrict__ out_w)
{
  const int blk = blockIdx.x;
  const int t = threadIdx.x, wave = t >> 6, lane = t & 63;
  __shared__ float smem[4 * DD];   // multi-purpose: partials / xs+ks / P-combine
  __shared__ float sred[256];
  __shared__ float sm4[4], sz4[4];
  __shared__ int sflag;

  int* cnt1    = ctrl;        // [16] phase-1 tile completion per batch
  int* vflag   = ctrl + 16;   // [16] v,c ready per batch
  int* cnt2    = ctrl + 32;   // [16] phase-2 tile completion per batch
  int* alldone = ctrl + 48;   // [1]  batches finalized

  // ---------------- phase 1: xsum partials (+ inline v,c for last finisher) ----
  for (int r = 0; r < 2; ++r) {
    const int T = blk + r * NBLK;        // batch-major tile id
    const int b = T >> 7, j = T & (TPB - 1);
    const float* xp = x + ((size_t)b * NN + (size_t)j * TROWS) * DD;
    float4 acc = make_float4(0.f, 0.f, 0.f, 0.f);
    for (int rr = wave; rr < TROWS; rr += 4) {
      float4 xv = *(const float4*)(xp + (size_t)rr * DD + lane * 4);
      acc.x += xv.x; acc.y += xv.y; acc.z += xv.z; acc.w += xv.w;
    }
    *(float4*)&smem[wave * DD + lane * 4] = acc;
    __syncthreads();
    part[((size_t)b * TPB + j) * DD + t] =
        smem[t] + smem[DD + t] + smem[2 * DD + t] + smem[3 * DD + t];
    __threadfence();                      // make part visible before counting
    __syncthreads();
    if (t == 0) sflag = (atomicAdd(&cnt1[b], 1) == TPB - 1);
    __syncthreads();
    if (sflag) {                          // ---- inline kB for batch b ----
      __threadfence();                    // acquire others' part writes
      float a2 = 0.f;
      for (int jj = 0; jj < TPB; ++jj) a2 += part[((size_t)b * TPB + jj) * DD + t];
      smem[t] = a2;                       // xs
      __syncthreads();
      float kacc = (float)NN * bk[t];
      const float4* wr = (const float4*)(Wk + (size_t)t * DD);
#pragma unroll 4
      for (int j4 = 0; j4 < DD / 4; ++j4) {
        float4 w = wr[j4];
        kacc += w.x * smem[4*j4] + w.y * smem[4*j4+1] + w.z * smem[4*j4+2] + w.w * smem[4*j4+3];
      }
      smem[DD + t] = kacc;                // ks
      __syncthreads();
      float vacc = 0.f;
#pragma unroll 4
      for (int o = 0; o < DD; ++o) vacc += Wq[(size_t)o * DD + t] * smem[DD + o];
      v[b * DD + t] = vacc;
      sred[t] = bq[t] * smem[DD + t];
      __syncthreads();
      for (int s = 128; s > 0; s >>= 1) { if (t < s) sred[t] += sred[t + s]; __syncthreads(); }
      if (t == 0) c[b] = sred[0];
      __threadfence();                    // release v,c
      if (t == 0) atomicExch(&vflag[b], 1);
    }
    __syncthreads();
  }

  // ---------------- phase 2: flash pass (+ inline per-batch finalize) ----------
  for (int r = 0; r < 2; ++r) {
    const int T = blk + r * NBLK;
    const int b = T >> 7, j = T & (TPB - 1);
    if (t == 0) { while (atomicAdd(&vflag[b], 0) == 0) __builtin_amdgcn_s_sleep(2); }
    __syncthreads();
    __threadfence();                      // acquire v,c
    const float4 vl = *(const float4*)(v + b * DD + lane * 4);
    const float cb = c[b];
    const float scale = 0.0625f;          // 1/sqrt(256)
    const int n0 = j * TROWS + wave * (TROWS / 4);
    const float* xb = x + (size_t)b * NN * DD;
    float m = -INFINITY, Z = 0.f;
    float4 P = make_float4(0.f, 0.f, 0.f, 0.f);
    for (int i = 0; i < TROWS / 4; ++i) {
      const int n = n0 + i;
      float4 xr = *(const float4*)(xb + (size_t)n * DD + lane * 4);
      float dot = xr.x * vl.x + xr.y * vl.y + xr.z * vl.z + xr.w * vl.w;
#pragma unroll
      for (int off = 32; off >= 1; off >>= 1) dot += __shfl_xor(dot, off, 64);
      const float s = (dot + cb) * scale;
      if (lane == 0) scores[(size_t)b * NN + n] = s;
      const float mn = fmaxf(m, s);
      const float alpha = __expf(m - mn); // m==-inf -> 0
      const float e = __expf(s - mn);
      Z = Z * alpha + e;
      P.x = P.x * alpha + e * xr.x; P.y = P.y * alpha + e * xr.y;
      P.z = P.z * alpha + e * xr.z; P.w = P.w * alpha + e * xr.w;
      m = mn;
    }
    __syncthreads();                      // smem free from previous use
    *(float4*)&smem[wave * DD + lane * 4] = P;
    if (lane == 0) { sm4[wave] = m; sz4[wave] = Z; }
    __syncthreads();
    const float M = fmaxf(fmaxf(sm4[0], sm4[1]), fmaxf(sm4[2], sm4[3]));
    const float e0 = __expf(sm4[0] - M), e1 = __expf(sm4[1] - M);
    const float e2 = __expf(sm4[2] - M), e3 = __expf(sm4[3] - M);
    const float Pd = smem[t] * e0 + smem[DD + t] * e1 + smem[2 * DD + t] * e2 + smem[3 * DD + t] * e3;
    const size_t idx = (size_t)b * TPB + j;
    pP[idx * DD + t] = Pd;
    if (t == 0) { pm[idx] = M; pz[idx] = sz4[0]*e0 + sz4[1]*e1 + sz4[2]*e2 + sz4[3]*e3; }
    __threadfence();                      // make tile results visible
    __syncthreads();
    if (t == 0) sflag = (atomicAdd(&cnt2[b], 1) == TPB - 1);
    __syncthreads();
    if (sflag) {                          // ---- inline finalize for batch b ----
      __threadfence();                    // acquire all tiles of batch b
      const size_t base = (size_t)b * TPB;
      sred[t] = (t < TPB) ? pm[base + t] : -INFINITY;
      __syncthreads();
      for (int s = 128; s > 0; s >>= 1) { if (t < s) sred[t] = fmaxf(sred[t], sred[t + s]); __syncthreads(); }
      const float M2 = sred[0];
      __syncthreads();
      sred[t] = (t < TPB) ? pz[base + t] * __expf(pm[base + t] - M2) : 0.f;
      __syncthreads();
      for (int s = 128; s > 0; s >>= 1) { if (t < s) sred[t] += sred[t + s]; __syncthreads(); }
      const float rZ = 1.f / sred[0];
      float acc = 0.f;
      for (int jj = 0; jj < TPB; ++jj)
        acc += pP[(base + jj) * DD + t] * __expf(pm[base + jj] - M2);
      out_agg[b * DD + t] = acc * rZ;
      if (t == 0) { Mb[b] = M2; rZb[b] = rZ; }
      __threadfence();                    // release Mb,rZb (+ transitively scores)
      if (t == 0) atomicAdd(alldone, 1);
    }
    __syncthreads();
  }

  // ---------------- tail: average_customer_weights (blocks 0..63) ------------
  if (blk < NN / 256) {
    if (t == 0) { while (atomicAdd(alldone, 0) < BB) __builtin_amdgcn_s_sleep(2); }
    __syncthreads();
    __threadfence();
    __shared__ float sM[BB], sR[BB];
    if (t < BB) { sM[t] = Mb[t]; sR[t] = rZb[t]; }
    __syncthreads();
    const int n = blk * 256 + t;
    float acc = 0.f;
#pragma unroll
    for (int bb = 0; bb < BB; ++bb)
      acc += __expf(scores[(size_t)bb * NN + n] - sM[bb]) * sR[bb];
    out_w[n] = acc * (1.f / (float)BB);
  }
}

extern "C" void kernel_launch(void* const* d_in, const int* in_sizes, int n_in,
                              void* d_out, int out_size, void* d_ws, size_t ws_size,
                              hipStream_t stream) {
  const float* x  = (const float*)d_in[0];
  const float* Wq = (const float*)d_in[1];
  const float* bq = (const float*)d_in[2];
  const float* Wk = (const float*)d_in[3];
  const float* bk = (const float*)d_in[4];

  float* out  = (float*)d_out;
  float* agg  = out;             // [16, 256]
  float* avgw = out + BB * DD;   // [16384]

  // control block first (64 ints), float workspace after 256 B
  int* ctrl = (int*)d_ws;
  float* ws = (float*)((char*)d_ws + 256);
  float* part   = ws;  ws += (size_t)BB * TPB * DD;  // 524288
  float* v      = ws;  ws += BB * DD;                // 4096
  float* c      = ws;  ws += BB;                     // 16
  float* scores = ws;  ws += (size_t)BB * NN;        // 262144
  float* pm     = ws;  ws += BB * TPB;               // 2048
  float* pz     = ws;  ws += BB * TPB;               // 2048
  float* pP     = ws;  ws += (size_t)BB * TPB * DD;  // 524288
  float* Mb     = ws;  ws += BB;
  float* rZb    = ws;  ws += BB;

  hipMemsetAsync(ctrl, 0, 64 * sizeof(int), stream);
  fused_all<<<NBLK, 256, 0, stream>>>(x, Wq, bq, Wk, bk,
                                      part, v, c, scores, pm, pz, pP, Mb, rZb,
                                      ctrl, agg, avgw);
}

// Round 5
// 485.515 us; speedup vs baseline: 1.8381x; 1.8381x over previous
//
#include <hip/hip_runtime.h>
#include <math.h>

// Problem shapes (fixed by setup_inputs)
#define BB 16
#define NN 16384
#define DD 256      // == O
#define TPB 128     // tiles (blocks) per batch, both passes
#define TROWS 128   // rows per tile

// ---------------- kernel 1: xsum partials + inline (v,c) via last-block ----
// grid (TPB, BB). Last-finishing block of each batch computes v_b, c_b.
// One fence + one atomic per block; NO spin-waits anywhere.
__global__ __launch_bounds__(256) void k1f(const float* __restrict__ x,
                                           const float* __restrict__ Wq,
                                           const float* __restrict__ bq,
                                           const float* __restrict__ Wk,
                                           const float* __restrict__ bk,
                                           float* __restrict__ part,
                                           float* __restrict__ v,
                                           float* __restrict__ c,
                                           int* __restrict__ cnt1) {
  const int b = blockIdx.y, j = blockIdx.x;
  const int t = threadIdx.x, wave = t >> 6, lane = t & 63;
  __shared__ float smem[4 * DD];
  __shared__ float sred[256];
  __shared__ int sflag;

  const float* xp = x + ((size_t)b * NN + (size_t)j * TROWS) * DD;
  float4 acc = make_float4(0.f, 0.f, 0.f, 0.f);
  for (int r = wave; r < TROWS; r += 4) {
    float4 xv = *(const float4*)(xp + (size_t)r * DD + lane * 4);
    acc.x += xv.x; acc.y += xv.y; acc.z += xv.z; acc.w += xv.w;
  }
  *(float4*)&smem[wave * DD + lane * 4] = acc;
  __syncthreads();
  part[((size_t)b * TPB + j) * DD + t] =
      smem[t] + smem[DD + t] + smem[2 * DD + t] + smem[3 * DD + t];
  __threadfence();   // release our part tile
  __syncthreads();
  if (t == 0) sflag = (atomicAdd(&cnt1[b], 1) == TPB - 1);
  __syncthreads();
  if (!sflag) return;

  // ---- last block of batch b: xsum -> ksum -> v, c ----
  __threadfence();   // acquire all part tiles of batch b
  float a2 = 0.f;
  for (int jj = 0; jj < TPB; ++jj) a2 += part[((size_t)b * TPB + jj) * DD + t];
  smem[t] = a2;      // xs
  __syncthreads();
  float kacc = (float)NN * bk[t];
  const float4* wr = (const float4*)(Wk + (size_t)t * DD);
#pragma unroll 4
  for (int j4 = 0; j4 < DD / 4; ++j4) {
    float4 w = wr[j4];
    kacc += w.x * smem[4*j4] + w.y * smem[4*j4+1] + w.z * smem[4*j4+2] + w.w * smem[4*j4+3];
  }
  smem[DD + t] = kacc;  // ks
  __syncthreads();
  float vacc = 0.f;
#pragma unroll 4
  for (int o = 0; o < DD; ++o) vacc += Wq[(size_t)o * DD + t] * smem[DD + o];
  v[b * DD + t] = vacc;
  sred[t] = bq[t] * smem[DD + t];
  __syncthreads();
  for (int s = 128; s > 0; s >>= 1) { if (t < s) sred[t] += sred[t + s]; __syncthreads(); }
  if (t == 0) c[b] = sred[0];
  // visibility to kernel 2 is guaranteed by the dispatch boundary
}

// ---------------- kernel 2: flash pass + inline per-batch finalize ----------
// grid (TPB, BB). Last-finishing block of each batch computes
// aggregated_feature[b], Mb[b], rZb[b]. No spins.
__global__ __launch_bounds__(256) void k3f(const float* __restrict__ x,
                                           const float* __restrict__ v,
                                           const float* __restrict__ c,
                                           float* __restrict__ scores,
                                           float* __restrict__ pm,
                                           float* __restrict__ pz,
                                           float* __restrict__ pP,
                                           float* __restrict__ out_agg,
                                           float* __restrict__ Mb,
                                           float* __restrict__ rZb,
                                           int* __restrict__ cnt2) {
  const int b = blockIdx.y, j = blockIdx.x;
  const int t = threadIdx.x, wave = t >> 6, lane = t & 63;
  __shared__ float smem[4 * DD];
  __shared__ float sred[256];
  __shared__ float sm4[4], sz4[4];
  __shared__ int sflag;

  const float scale = 0.0625f;  // 1/sqrt(256)
  const float4 vl = *(const float4*)(v + b * DD + lane * 4);
  const float cb = c[b];
  const int n0 = j * TROWS + wave * (TROWS / 4);
  const float* xb = x + (size_t)b * NN * DD;

  float m = -INFINITY, Z = 0.f;
  float4 P = make_float4(0.f, 0.f, 0.f, 0.f);

  for (int i = 0; i < TROWS / 4; ++i) {
    const int n = n0 + i;
    float4 xr = *(const float4*)(xb + (size_t)n * DD + lane * 4);
    float dot = xr.x * vl.x + xr.y * vl.y + xr.z * vl.z + xr.w * vl.w;
#pragma unroll
    for (int off = 32; off >= 1; off >>= 1) dot += __shfl_xor(dot, off, 64);
    const float s = (dot + cb) * scale;
    if (lane == 0) scores[(size_t)b * NN + n] = s;
    // wave-uniform branch: s identical on all 64 lanes
    if (s > m) {            // rescale path (also first iteration: exp(-inf)=0)
      const float alpha = __expf(m - s);
      Z = Z * alpha + 1.f;
      P.x = P.x * alpha + xr.x; P.y = P.y * alpha + xr.y;
      P.z = P.z * alpha + xr.z; P.w = P.w * alpha + xr.w;
      m = s;
    } else {                // common path: no rescale
      const float e = __expf(s - m);
      Z += e;
      P.x += e * xr.x; P.y += e * xr.y;
      P.z += e * xr.z; P.w += e * xr.w;
    }
  }

  *(float4*)&smem[wave * DD + lane * 4] = P;
  if (lane == 0) { sm4[wave] = m; sz4[wave] = Z; }
  __syncthreads();
  const float M = fmaxf(fmaxf(sm4[0], sm4[1]), fmaxf(sm4[2], sm4[3]));
  const float e0 = __expf(sm4[0] - M), e1 = __expf(sm4[1] - M);
  const float e2 = __expf(sm4[2] - M), e3 = __expf(sm4[3] - M);
  const float Pd = smem[t] * e0 + smem[DD + t] * e1 + smem[2 * DD + t] * e2 + smem[3 * DD + t] * e3;
  const size_t idx = (size_t)b * TPB + j;
  pP[idx * DD + t] = Pd;
  if (t == 0) { pm[idx] = M; pz[idx] = sz4[0]*e0 + sz4[1]*e1 + sz4[2]*e2 + sz4[3]*e3; }
  __threadfence();   // release this tile's pP/pm/pz
  __syncthreads();
  if (t == 0) sflag = (atomicAdd(&cnt2[b], 1) == TPB - 1);
  __syncthreads();
  if (!sflag) return;

  // ---- last block of batch b: finalize ----
  __threadfence();   // acquire all tiles of batch b
  const size_t base = (size_t)b * TPB;
  sred[t] = (t < TPB) ? pm[base + t] : -INFINITY;
  __syncthreads();
  for (int s = 128; s > 0; s >>= 1) { if (t < s) sred[t] = fmaxf(sred[t], sred[t + s]); __syncthreads(); }
  const float M2 = sred[0];
  __syncthreads();
  sred[t] = (t < TPB) ? pz[base + t] * __expf(pm[base + t] - M2) : 0.f;
  __syncthreads();
  for (int s = 128; s > 0; s >>= 1) { if (t < s) sred[t] += sred[t + s]; __syncthreads(); }
  const float rZ = 1.f / sred[0];
  float acc = 0.f;
  for (int jj = 0; jj < TPB; ++jj)
    acc += pP[(base + jj) * DD + t] * __expf(pm[base + jj] - M2);
  out_agg[b * DD + t] = acc * rZ;
  if (t == 0) { Mb[b] = M2; rZb[b] = rZ; }
}

// ---------------- kernel 3: average_customer_weights ----------------
__global__ __launch_bounds__(256) void kw(const float* __restrict__ scores,
                                          const float* __restrict__ Mb,
                                          const float* __restrict__ rZb,
                                          float* __restrict__ out_w) {
  const int t = threadIdx.x;
  __shared__ float sM[BB], sR[BB];
  if (t < BB) { sM[t] = Mb[t]; sR[t] = rZb[t]; }
  __syncthreads();
  const int n = blockIdx.x * 256 + t;
  float acc = 0.f;
#pragma unroll
  for (int bb = 0; bb < BB; ++bb)
    acc += __expf(scores[(size_t)bb * NN + n] - sM[bb]) * sR[bb];
  out_w[n] = acc * (1.f / (float)BB);
}

extern "C" void kernel_launch(void* const* d_in, const int* in_sizes, int n_in,
                              void* d_out, int out_size, void* d_ws, size_t ws_size,
                              hipStream_t stream) {
  const float* x  = (const float*)d_in[0];
  const float* Wq = (const float*)d_in[1];
  const float* bq = (const float*)d_in[2];
  const float* Wk = (const float*)d_in[3];
  const float* bk = (const float*)d_in[4];

  float* out  = (float*)d_out;
  float* agg  = out;             // [16, 256]
  float* avgw = out + BB * DD;   // [16384]

  int* ctrl = (int*)d_ws;        // cnt1[16], cnt2[16]
  int* cnt1 = ctrl;
  int* cnt2 = ctrl + 16;
  float* ws = (float*)((char*)d_ws + 256);
  float* part   = ws;  ws += (size_t)BB * TPB * DD;  // 524288
  float* v      = ws;  ws += BB * DD;                // 4096
  float* c      = ws;  ws += BB;                     // 16
  float* scores = ws;  ws += (size_t)BB * NN;        // 262144
  float* pm     = ws;  ws += BB * TPB;               // 2048
  float* pz     = ws;  ws += BB * TPB;               // 2048
  float* pP     = ws;  ws += (size_t)BB * TPB * DD;  // 524288
  float* Mb     = ws;  ws += BB;
  float* rZb    = ws;  ws += BB;

  hipMemsetAsync(ctrl, 0, 32 * sizeof(int), stream);
  k1f<<<dim3(TPB, BB), 256, 0, stream>>>(x, Wq, bq, Wk, bk, part, v, c, cnt1);
  k3f<<<dim3(TPB, BB), 256, 0, stream>>>(x, v, c, scores, pm, pz, pP, agg, Mb, rZb, cnt2);
  kw<<<NN / 256, 256, 0, stream>>>(scores, Mb, rZb, avgw);
}

// Round 7
// 115.673 us; speedup vs baseline: 7.7152x; 4.1973x over previous
//
#include <hip/hip_runtime.h>
#include <math.h>

// Problem shapes (fixed by setup_inputs)
#define BB 16
#define NN 16384
#define DD 256     // == O
#define NS1 128    // blocks per batch, pass 1 (xsum)
#define NS3 128    // blocks per batch, pass 2 (scores + flash partials)

typedef float floatx4 __attribute__((ext_vector_type(4)));

__device__ __forceinline__ floatx4 ntload4(const float* p) {
  return __builtin_nontemporal_load((const floatx4*)p);
}

// ---------------- K1: partial column-sums of x ----------------
// grid (NS1, BB), block 256 (4 waves). Each block streams 128 rows (128 KB).
__global__ __launch_bounds__(256) void k1_xsum_part(const float* __restrict__ x,
                                                    float* __restrict__ part) {
  const int b = blockIdx.y, blk = blockIdx.x;
  const int wave = threadIdx.x >> 6, lane = threadIdx.x & 63;
  const int rows = NN / NS1;  // 128
  const float* xp = x + ((size_t)b * NN + (size_t)blk * rows) * DD;
  floatx4 acc = {0.f, 0.f, 0.f, 0.f};
  for (int r = wave; r < rows; r += 4) {
    acc += ntload4(xp + (size_t)r * DD + lane * 4);
  }
  __shared__ float sP[4][DD];
  *(floatx4*)&sP[wave][lane * 4] = acc;
  __syncthreads();
  const int t = threadIdx.x;
  part[((size_t)b * NS1 + blk) * DD + t] = sP[0][t] + sP[1][t] + sP[2][t] + sP[3][t];
}

// ---------------- K2: part -> xsum -> ksum -> v, c ----------------
__global__ __launch_bounds__(256) void k2_prep(const float* __restrict__ part,
                                               const float* __restrict__ Wq,
                                               const float* __restrict__ bq,
                                               const float* __restrict__ Wk,
                                               const float* __restrict__ bk,
                                               float* __restrict__ v,
                                               float* __restrict__ c) {
  const int b = blockIdx.x, t = threadIdx.x;
  __shared__ float xs[DD];
  __shared__ float ks[DD];
  __shared__ float red[256];

  float acc = 0.f;
  for (int blk = 0; blk < NS1; ++blk) acc += part[((size_t)b * NS1 + blk) * DD + t];
  xs[t] = acc;
  __syncthreads();

  // ksum[o] = Wk[o,:] . xsum + N*bk[o]
  float kacc = (float)NN * bk[t];
  const float4* wkrow4 = (const float4*)(Wk + (size_t)t * DD);
#pragma unroll 4
  for (int j4 = 0; j4 < DD / 4; ++j4) {
    const float4 w = wkrow4[j4];
    kacc += w.x * xs[4 * j4] + w.y * xs[4 * j4 + 1] + w.z * xs[4 * j4 + 2] + w.w * xs[4 * j4 + 3];
  }
  ks[t] = kacc;
  __syncthreads();

  // v[d] = sum_o Wq[o,d] * ksum[o]  (coalesced over t)
  float vacc = 0.f;
  for (int o = 0; o < DD; ++o) vacc += Wq[(size_t)o * DD + t] * ks[o];
  v[b * DD + t] = vacc;

  // c = bq . ksum
  red[t] = bq[t] * ks[t];
  __syncthreads();
  for (int s = 128; s > 0; s >>= 1) {
    if (t < s) red[t] += red[t + s];
    __syncthreads();
  }
  if (t == 0) c[b] = red[0];
}

// ---------------- K3: main pass — scores + flash partials ----------------
__global__ __launch_bounds__(256) void k3_main(const float* __restrict__ x,
                                               const float* __restrict__ v,
                                               const float* __restrict__ c,
                                               float* __restrict__ scores,
                                               float* __restrict__ pm,
                                               float* __restrict__ pz,
                                               float* __restrict__ pP) {
  const int b = blockIdx.y, blk = blockIdx.x;
  const int wave = threadIdx.x >> 6, lane = threadIdx.x & 63;
  const float scale = 0.0625f;  // 1/sqrt(256)

  const floatx4 vl = *(const floatx4*)(v + b * DD + lane * 4);
  const float cb = c[b];
  const int rows_per_block = NN / NS3;          // 128
  const int rows_per_wave = rows_per_block / 4; // 32
  const int n0 = blk * rows_per_block + wave * rows_per_wave;
  const float* xb = x + (size_t)b * NN * DD;

  float m = -INFINITY, Z = 0.f;
  floatx4 P = {0.f, 0.f, 0.f, 0.f};

  for (int i = 0; i < rows_per_wave; ++i) {
    const int n = n0 + i;
    const floatx4 xr = ntload4(xb + (size_t)n * DD + lane * 4);
    const floatx4 prod = xr * vl;
    float dot = prod.x + prod.y + prod.z + prod.w;
#pragma unroll
    for (int off = 32; off >= 1; off >>= 1) dot += __shfl_xor(dot, off, 64);
    const float s = (dot + cb) * scale;
    if (lane == 0) scores[(size_t)b * NN + n] = s;
    // wave-uniform branch (s identical across lanes after butterfly)
    if (s > m) {            // rescale path (covers first iter: exp(-inf)=0)
      const float alpha = __expf(m - s);
      Z = Z * alpha + 1.f;
      P = P * alpha + xr;
      m = s;
    } else {                // common path
      const float e = __expf(s - m);
      Z += e;
      P += xr * e;
    }
  }

  // combine the 4 waves of this block
  __shared__ float sm[4], sz[4];
  __shared__ float sP[4][DD];
  *(floatx4*)&sP[wave][lane * 4] = P;
  if (lane == 0) { sm[wave] = m; sz[wave] = Z; }
  __syncthreads();

  const int t = threadIdx.x;
  const float M = fmaxf(fmaxf(sm[0], sm[1]), fmaxf(sm[2], sm[3]));
  const float e0 = __expf(sm[0] - M), e1 = __expf(sm[1] - M);
  const float e2 = __expf(sm[2] - M), e3 = __expf(sm[3] - M);
  const float Pd = sP[0][t] * e0 + sP[1][t] * e1 + sP[2][t] * e2 + sP[3][t] * e3;
  const size_t idx = (size_t)b * NS3 + blk;
  pP[idx * DD + t] = Pd;
  if (t == 0) {
    pm[idx] = M;
    pz[idx] = sz[0] * e0 + sz[1] * e1 + sz[2] * e2 + sz[3] * e3;
  }
}

// ---------------- K45: merged finalization ----------------
// Blocks 0..15 (role A): aggregated_feature[b].
// Blocks 16..79 (role B): average_customer_weights — each block redundantly
// recomputes all 16 (M_b, 1/Z_b) from pm/pz via 16-lane-group shuffle reduces.
__global__ __launch_bounds__(256) void k45_final(const float* __restrict__ pm,
                                                 const float* __restrict__ pz,
                                                 const float* __restrict__ pP,
                                                 const float* __restrict__ scores,
                                                 float* __restrict__ out_agg,
                                                 float* __restrict__ out_w) {
  const int t = threadIdx.x;
  if (blockIdx.x < BB) {
    // ---- role A ----
    const int b = blockIdx.x;
    __shared__ float red[256];
    const size_t base = (size_t)b * NS3;

    red[t] = (t < NS3) ? pm[base + t] : -INFINITY;
    __syncthreads();
    for (int s = 128; s > 0; s >>= 1) {
      if (t < s) red[t] = fmaxf(red[t], red[t + s]);
      __syncthreads();
    }
    const float M = red[0];
    __syncthreads();

    red[t] = (t < NS3) ? pz[base + t] * __expf(pm[base + t] - M) : 0.f;
    __syncthreads();
    for (int s = 128; s > 0; s >>= 1) {
      if (t < s) red[t] += red[t + s];
      __syncthreads();
    }
    const float rZ = 1.f / red[0];

    float acc = 0.f;
    for (int blk = 0; blk < NS3; ++blk)
      acc += pP[(base + blk) * DD + t] * __expf(pm[base + blk] - M);
    out_agg[b * DD + t] = acc * rZ;
  } else {
    // ---- role B ----
    const int wb = blockIdx.x - BB;
    __shared__ float sM[BB], sR[BB];
    const int b = t >> 4;
    const int i = t & 15;
    const size_t base = (size_t)b * NS3 + i * 8;

    float mloc = -INFINITY;
#pragma unroll
    for (int k = 0; k < 8; ++k) mloc = fmaxf(mloc, pm[base + k]);
#pragma unroll
    for (int off = 8; off >= 1; off >>= 1) mloc = fmaxf(mloc, __shfl_xor(mloc, off, 64));
    const float M = mloc;

    float zloc = 0.f;
#pragma unroll
    for (int k = 0; k < 8; ++k) zloc += pz[base + k] * __expf(pm[base + k] - M);
#pragma unroll
    for (int off = 8; off >= 1; off >>= 1) zloc += __shfl_xor(zloc, off, 64);

    if (i == 0) { sM[b] = M; sR[b] = 1.f / zloc; }
    __syncthreads();

    const int n = wb * 256 + t;
    float acc = 0.f;
#pragma unroll
    for (int bb = 0; bb < BB; ++bb)
      acc += __expf(scores[(size_t)bb * NN + n] - sM[bb]) * sR[bb];
    out_w[n] = acc * (1.f / BB);
  }
}

extern "C" void kernel_launch(void* const* d_in, const int* in_sizes, int n_in,
                              void* d_out, int out_size, void* d_ws, size_t ws_size,
                              hipStream_t stream) {
  const float* x  = (const float*)d_in[0];
  const float* Wq = (const float*)d_in[1];
  const float* bq = (const float*)d_in[2];
  const float* Wk = (const float*)d_in[3];
  const float* bk = (const float*)d_in[4];

  float* out  = (float*)d_out;
  float* agg  = out;             // [16, 256]
  float* avgw = out + BB * DD;   // [16384]

  float* ws = (float*)d_ws;
  float* part   = ws;  ws += (size_t)BB * NS1 * DD;  // 524288
  float* v      = ws;  ws += BB * DD;                // 4096
  float* c      = ws;  ws += BB;                     // 16
  float* scores = ws;  ws += (size_t)BB * NN;        // 262144
  float* pm     = ws;  ws += BB * NS3;               // 2048
  float* pz     = ws;  ws += BB * NS3;               // 2048
  float* pP     = ws;  ws += (size_t)BB * NS3 * DD;  // 524288

  k1_xsum_part<<<dim3(NS1, BB), 256, 0, stream>>>(x, part);
  k2_prep<<<BB, 256, 0, stream>>>(part, Wq, bq, Wk, bk, v, c);
  k3_main<<<dim3(NS3, BB), 256, 0, stream>>>(x, v, c, scores, pm, pz, pP);
  k45_final<<<BB + NN / 256, 256, 0, stream>>>(pm, pz, pP, scores, agg, avgw);
}